// Round 6
// baseline (251.492 us; speedup 1.0000x reference)
//
#include <hip/hip_runtime.h>

// Problem constants (from reference)
#define Nn 1024
#define Hh 96
#define Ee 16384
#define IN_K 9       // IN_RAW-1
#define IN_STRIDE 10 // x is (N, 10), we use first 9 cols
#define NH (Nn * Hh)
#define XS 128       // padded row stride for x-like (N,96) buffers
#define SLOTS 64     // per-row neighbor capacity (Poisson(16); P(>64) ~ 0)
#define NBLK 256     // persistent grid: 1024 thr, 34.6KB LDS -> >=2 blocks/CU capacity

__device__ __forceinline__ float sigf(float v) {
    return __builtin_amdgcn_rcpf(1.0f + __expf(-v));
}
__device__ __forceinline__ float tanhfast(float v) {
    float e = __expf(2.0f * v);
    return (e - 1.0f) * __builtin_amdgcn_rcpf(e + 1.0f);
}
__device__ __forceinline__ float leakyf(float v) {
    return v >= 0.0f ? v : 0.01f * v;
}

struct Params {
    const float* x_in; const int* ei; const int* adj;
    const float* W_init; const float* b_init;
    const float* W_ggc; const float* W_ih; const float* W_hh;
    const float* b_ih; const float* b_hh;
    const float* Wa1; const float* ba1; const float* Wa2; const float* ba2;
    const float* Wo1; const float* bo1; const float* Wo2; const float* bo2;
    const float* Wp1; const float* bp1; const float* Wp2; const float* bp2;
    float* out;
    float* xA; float* xB; float* xC; float* Ei; float* EjT;
    float* Wt_hh; float* Wf; float* Wt_a1i; float* Wt_a1j;
    float* Wt_o1; float* Wt_o2;
    int* bar;
};

// LDS union across phases. Max member = attn struct: ~34.6 KB.
union Shm {
    struct {                        // gru phase
        int   cnt[4];               // per-row edge counts (true counts)
        int   lst[4][SLOTS];        // per-row source lists
        float Pm[4][Hh];            // per-row gather mean
        float Xr[4][Hh];            // per-row x
        float Xo[4][Hh];            // per-row GRU output
        float gd[6][4][Hh];         // full-K gate dots [gate][row][h]
        float redp[2][4][4][Hh];    // proj partials [w][q][row][h]
    } g;
    struct {                        // attn phase
        float sm[7168];             // coeffs (4x1024) @0 + partials @4096
        float eis[4 * Hh];          // Ei rows staged
        float wa2s[Hh];             // Wa2 staged
        float hd[3][4][Hh];         // fused head temporaries (u1 only)
    } a;
};

// Grid barrier — third design, both prior failure modes addressed:
//  * r1/r3 failure: ACQUIRE polls emit buffer_inv each iteration ->
//    continuous XCD-L2 flash-invalidate storms (191us GPU for 60us work).
//  * r2 failure (suspected): pure RELAXED poll may be served by a stale
//    XCD L2 line while the fetch_add lands at the IF coherence point ->
//    infinite spin.
//  Fix: poll with an atomic RMW (fetch_add 0). Atomics ALWAYS execute at
//  the device coherence point -> never stale (no hang) AND no cache
//  invalidate (no storm). One RELEASE on arrival (buffer_wbl2: makes this
//  block's stores visible), one ACQUIRE on exit (buffer_inv: makes other
//  blocks' stores visible) — per block per barrier, like ROCm's own
//  cooperative grid sync.
__device__ __forceinline__ void gsync(int* bar, int idx) {
    __syncthreads();                 // all waves' stores issued (vmcnt drain)
    if (threadIdx.x == 0) {
        __hip_atomic_fetch_add(bar + idx, 1, __ATOMIC_RELEASE,
                               __HIP_MEMORY_SCOPE_AGENT);
        while (__hip_atomic_fetch_add(bar + idx, 0, __ATOMIC_RELAXED,
                                      __HIP_MEMORY_SCOPE_AGENT) < NBLK) {
            __builtin_amdgcn_s_sleep(8);
        }
        (void)__hip_atomic_load(bar + idx, __ATOMIC_ACQUIRE,
                                __HIP_MEMORY_SCOPE_AGENT);
    }
    __syncthreads();
}

// ---------------- gru phase: 4 rows/block, phases A0..E (r5-verified) ------
__device__ __forceinline__ void gru_phase(const Params& p, Shm& sh,
                                          const float* xin, float* xout)
{
    int tid = threadIdx.x;
    int i0 = blockIdx.x * 4;

    // A0: build this block's neighbor lists from the (constant) edge array
    if (tid < 4) sh.g.cnt[tid] = 0;
    __syncthreads();
    for (int e = tid; e < Ee; e += 1024) {
        int tgt = p.ei[Ee + e];             // coalesced, L2-hit
        unsigned r = (unsigned)(tgt - i0);
        if (r < 4u) {
            int slot = atomicAdd(&sh.g.cnt[r], 1);
            if (slot < SLOTS) sh.g.lst[r][slot] = p.ei[e];
        }
    }
    __syncthreads();

    // A1: gather + mean, 384 threads (r, h), full row per thread
    if (tid < 384) {
        int h = tid % Hh, rr = tid / Hh;
        int d = sh.g.cnt[rr];
        int dc = d < SLOTS ? d : SLOTS;
        float acc = 0.0f;
        for (int s = 0; s < dc; ++s)
            acc += xin[sh.g.lst[rr][s] * XS + h];  // lst: LDS broadcast
        float inv = __builtin_amdgcn_rcpf(fmaxf((float)d, 1.0f));
        sh.g.Pm[rr][h] = acc * inv;
        sh.g.Xr[rr][h] = xin[(i0 + rr) * XS + h];
    }
    __syncthreads();

    // B: 6 gate dots, 576 threads (gate, h), full K=96, 4 rows in registers
    if (tid < 576) {
        int h = tid % Hh;
        int g = tid / Hh;              // 0..2: i-path (Wf/Pm), 3..5: h-path
        bool ipath = g < 3;
        int gc = ipath ? g : g - 3;
        const float* W = (ipath ? p.Wf : p.Wt_hh) + gc * 96 + h;
        const float (*src)[Hh] = ipath ? sh.g.Pm : sh.g.Xr;
        float a0 = 0.f, a1 = 0.f, a2 = 0.f, a3 = 0.f;
#pragma unroll 8
        for (int k = 0; k < 96; ++k) {
            float w = W[k * 288];
            a0 += src[0][k] * w;
            a1 += src[1][k] * w;
            a2 += src[2][k] * w;
            a3 += src[3][k] * w;
        }
        sh.g.gd[g][0][h] = a0;
        sh.g.gd[g][1][h] = a1;
        sh.g.gd[g][2][h] = a2;
        sh.g.gd[g][3][h] = a3;
    }
    __syncthreads();

    // C: gate math, 384 threads (r, h)
    if (tid < 384) {
        int h = tid % Hh, rr = tid / Hh;
        float gir = p.b_ih[h]        + sh.g.gd[0][rr][h];
        float giz = p.b_ih[96 + h]   + sh.g.gd[1][rr][h];
        float gin = p.b_ih[192 + h]  + sh.g.gd[2][rr][h];
        float ghr = p.b_hh[h]        + sh.g.gd[3][rr][h];
        float ghz = p.b_hh[96 + h]   + sh.g.gd[4][rr][h];
        float ghn = p.b_hh[192 + h]  + sh.g.gd[5][rr][h];
        float r_  = sigf(gir + ghr);
        float z   = sigf(giz + ghz);
        float nn2 = tanhfast(gin + r_ * ghn);
        float xo  = (1.0f - z) * nn2 + z * sh.g.Xr[rr][h];
        xout[(i0 + rr) * XS + h] = xo;
        sh.g.Xo[rr][h] = xo;
    }
    __syncthreads();

    // D: attention projections, 768 threads (w, q, h), 24-k partials
    if (tid < 768) {
        int h = tid % Hh;
        int q = (tid / Hh) & 3;
        int w = tid / 384;             // 0 = i-proj, 1 = j-proj
        const float* Wp = (w ? p.Wt_a1j : p.Wt_a1i) + h;
        float a0 = 0.f, a1 = 0.f, a2 = 0.f, a3 = 0.f;
        int k0 = q * 24;
#pragma unroll 4
        for (int k = k0; k < k0 + 24; ++k) {
            float wv = Wp[k * 96];
            a0 += sh.g.Xo[0][k] * wv;
            a1 += sh.g.Xo[1][k] * wv;
            a2 += sh.g.Xo[2][k] * wv;
            a3 += sh.g.Xo[3][k] * wv;
        }
        sh.g.redp[w][q][0][h] = a0;
        sh.g.redp[w][q][1][h] = a1;
        sh.g.redp[w][q][2][h] = a2;
        sh.g.redp[w][q][3][h] = a3;
    }
    __syncthreads();

    // E: finalize projections, 768 threads (w, r, h)
    if (tid < 768) {
        int h = tid % Hh;
        int rr = (tid / Hh) & 3;
        int w = tid / 384;
        int n = i0 + rr;
        float s = sh.g.redp[w][0][rr][h] + sh.g.redp[w][1][rr][h]
                + sh.g.redp[w][2][rr][h] + sh.g.redp[w][3][rr][h];
        if (w == 0) p.Ei[n * Hh + h]  = __expf(-(s + p.ba1[h]));
        else        p.EjT[h * Nn + n] = __expf(-s);
    }
    // no trailing block sync: a gsync follows
}

// ---------------- attn coeff + row-GEMM (r5-verified body) -----------------
__device__ __forceinline__ void attn_coeff(const Params& p, Shm& sh,
                                           const float* xB)
{
    int tid = threadIdx.x;
    int i0 = blockIdx.x * 4;
    if (tid < 4 * Hh) sh.a.eis[tid] = p.Ei[i0 * Hh + tid];
    if (tid >= 512 && tid < 512 + Hh) sh.a.wa2s[tid - 512] = p.Wa2[tid - 512];
    {
        int j = tid;
        int m0 = p.adj[(i0 + 0) * Nn + j];
        int m1 = p.adj[(i0 + 1) * Nn + j];
        int m2 = p.adj[(i0 + 2) * Nn + j];
        int m3 = p.adj[(i0 + 3) * Nn + j];
        __syncthreads();
        float s0 = 0.f, s1 = 0.f, s2 = 0.f, s3 = 0.f;
#pragma unroll 8
        for (int k = 0; k < Hh; ++k) {
            float e = p.EjT[k * Nn + j];
            float wk = sh.a.wa2s[k];           // LDS broadcast
            s0 += __builtin_amdgcn_rcpf(fmaf(sh.a.eis[k], e, 1.0f)) * wk;
            s1 += __builtin_amdgcn_rcpf(fmaf(sh.a.eis[96 + k], e, 1.0f)) * wk;
            s2 += __builtin_amdgcn_rcpf(fmaf(sh.a.eis[192 + k], e, 1.0f)) * wk;
            s3 += __builtin_amdgcn_rcpf(fmaf(sh.a.eis[288 + k], e, 1.0f)) * wk;
        }
        float b2 = p.ba2[0];
        sh.a.sm[0 * Nn + j] = (m0 == 1) ? sigf(s0 + b2) : 0.0f;
        sh.a.sm[1 * Nn + j] = (m1 == 1) ? sigf(s1 + b2) : 0.0f;
        sh.a.sm[2 * Nn + j] = (m2 == 1) ? sigf(s2 + b2) : 0.0f;
        sh.a.sm[3 * Nn + j] = (m3 == 1) ? sigf(s3 + b2) : 0.0f;
    }
    __syncthreads();
    {
        int q = tid >> 7;
        int h = tid & 127;
        if (h < Hh) {
            int jb = q * 128;
            const float* xc = xB + jb * XS + h;
            const float* c0 = sh.a.sm + 0 * Nn + jb;
            const float* c1 = sh.a.sm + 1 * Nn + jb;
            const float* c2 = sh.a.sm + 2 * Nn + jb;
            const float* c3 = sh.a.sm + 3 * Nn + jb;
            float a0 = 0.f, a1 = 0.f, a2 = 0.f, a3 = 0.f;
#pragma unroll 4
            for (int j = 0; j < 128; ++j) {
                float xv = xc[j * XS];
                a0 += c0[j] * xv;
                a1 += c1[j] * xv;
                a2 += c2[j] * xv;
                a3 += c3[j] * xv;
            }
            sh.a.sm[4096 + ((q * 4 + 0) * Hh) + h] = a0;
            sh.a.sm[4096 + ((q * 4 + 1) * Hh) + h] = a1;
            sh.a.sm[4096 + ((q * 4 + 2) * Hh) + h] = a2;
            sh.a.sm[4096 + ((q * 4 + 3) * Hh) + h] = a3;
        }
    }
    __syncthreads();
}

__device__ __forceinline__ void attn_tail_u0(const Params& p, Shm& sh,
                                             float* xOut)
{
    int tid = threadIdx.x;
    int i0 = blockIdx.x * 4;
    if (tid < 4 * Hh) {
        int r = tid / Hh, h = tid - r * Hh;
        float v = 0.f;
#pragma unroll
        for (int q = 0; q < 8; ++q)
            v += sh.a.sm[4096 + ((q * 4 + r) * Hh) + h];
        xOut[(i0 + r) * XS + h] = v;
    }
}

__device__ __forceinline__ void attn_tail_u1(const Params& p, Shm& sh)
{
    int tid = threadIdx.x;
    int i0 = blockIdx.x * 4;
    if (tid < 4 * Hh) {
        int r = tid / Hh, h = tid - r * Hh;
        float v = 0.f;
#pragma unroll
        for (int q = 0; q < 8; ++q)
            v += sh.a.sm[4096 + ((q * 4 + r) * Hh) + h];
        sh.a.hd[0][r][h] = v;
    }
    __syncthreads();
    if (tid < 4 * Hh) {
        int r = tid / Hh, h = tid - r * Hh;
        const float* w = p.Wt_o1 + h;
        const float* xr = sh.a.hd[0][r];
        float acc = p.bo1[h];
        for (int k = 0; k < Hh; ++k) acc += xr[k] * w[k * 96];
        sh.a.hd[1][r][h] = leakyf(acc);
    }
    __syncthreads();
    if (tid < 4 * Hh) {
        int r = tid / Hh, h = tid - r * Hh;
        const float* w = p.Wt_o2 + h;
        const float* xr = sh.a.hd[1][r];
        float acc = p.bo2[h];
        for (int k = 0; k < Hh; ++k) acc += xr[k] * w[k * 96];
        sh.a.hd[2][r][h] = leakyf(acc);
    }
    __syncthreads();
    if (tid < 8) {
        int r = tid >> 1, which = tid & 1;
        const float* wp = which ? p.Wp2 : p.Wp1;
        const float* xr = sh.a.hd[2][r];
        float acc = 0.f;
        for (int k = 0; k < Hh; ++k) acc += xr[k] * wp[k];
        float b = which ? p.bp2[0] : p.bp1[0];
        p.out[which * Nn + i0 + r] = sigf(acc + b);
    }
}

// ---------------- fused persistent kernel ----------------------------------
__global__ __launch_bounds__(1024) void fused_kernel(Params p)
{
    __shared__ Shm sh;
    int tid = threadIdx.x;
    int blk = blockIdx.x;

    // ---- P0: setup spread over ALL blocks (no edge work needed — gru
    //      phases build their own LDS CSR from the constant edge array)
    {
        int gt = blk * 1024 + tid;
        if (gt < 64512) {   // transposes: Wt_hh 27648 + 4x9216
            int idx = gt;
            if (idx < 27648) {
                int k = idx / 288, c = idx % 288;
                p.Wt_hh[idx] = p.W_hh[c * 96 + k];
            } else if ((idx -= 27648) < 9216) {
                int k = idx / 96, h2 = idx % 96;
                p.Wt_a1i[idx] = p.Wa1[h2 * 192 + k];
            } else if ((idx -= 9216) < 9216) {
                int k = idx / 96, h2 = idx % 96;
                p.Wt_a1j[idx] = p.Wa1[h2 * 192 + 96 + k];
            } else if ((idx -= 9216) < 9216) {
                int k = idx / 96, j = idx % 96;
                p.Wt_o1[idx] = p.Wo1[j * 96 + k];
            } else {
                idx -= 9216;
                int k = idx / 96, j = idx % 96;
                p.Wt_o2[idx] = p.Wo2[j * 96 + k];
            }
        }
        // Wf fold redistributed across ALL blocks (job j = tid*256 + blk,
        // bijective over [0, 27648) for tid < 108): 96-iter dot each.
        if (tid < 108) {
            int j = tid * 256 + blk;
            int k = j / 288, c = j % 288;
            const float* g = p.W_ggc + k * 96;
            const float* w = p.W_ih + c * 96;
            float acc = 0.0f;
            for (int q = 0; q < 96; ++q) acc += g[q] * w[q];
            p.Wf[j] = acc;
        }
        if (gt < NH) {      // init linear
            int n = gt / Hh, j = gt - n * Hh;
            const float* xr = p.x_in + n * IN_STRIDE;
            const float* wr = p.W_init + j * IN_K;
            float acc = p.b_init[j];
#pragma unroll
            for (int k = 0; k < IN_K; ++k) acc += xr[k] * wr[k];
            p.xA[n * XS + j] = leakyf(acc);
        }
    }
    gsync(p.bar, 0);

    // ---- unroll 0: xA -> xB -> xC ----
    gru_phase(p, sh, p.xA, p.xB);
    gsync(p.bar, 1);
    attn_coeff(p, sh, p.xB);
    attn_tail_u0(p, sh, p.xC);
    gsync(p.bar, 2);

    // ---- unroll 1: xC -> xB -> (fused head) -> out ----
    gru_phase(p, sh, p.xC, p.xB);
    gsync(p.bar, 3);
    attn_coeff(p, sh, p.xB);
    attn_tail_u1(p, sh);
}

extern "C" void kernel_launch(void* const* d_in, const int* in_sizes, int n_in,
                              void* d_out, int out_size, void* d_ws, size_t ws_size,
                              hipStream_t stream)
{
    const float* x_in   = (const float*)d_in[0];
    const int*   ei     = (const int*)d_in[1];
    const int*   adj    = (const int*)d_in[2];
    const float* W_init = (const float*)d_in[3];
    const float* b_init = (const float*)d_in[4];
    const float* W_ggc  = (const float*)d_in[5];
    const float* W_ih   = (const float*)d_in[6];
    const float* W_hh   = (const float*)d_in[7];
    const float* b_ih   = (const float*)d_in[8];
    const float* b_hh   = (const float*)d_in[9];
    const float* Wa1    = (const float*)d_in[10];
    const float* ba1    = (const float*)d_in[11];
    const float* Wa2    = (const float*)d_in[12];
    const float* ba2    = (const float*)d_in[13];
    const float* Wo1    = (const float*)d_in[14];
    const float* bo1    = (const float*)d_in[15];
    const float* Wo2    = (const float*)d_in[16];
    const float* bo2    = (const float*)d_in[17];
    const float* Wp1    = (const float*)d_in[18];
    const float* bp1    = (const float*)d_in[19];
    const float* Wp2    = (const float*)d_in[20];
    const float* bp2    = (const float*)d_in[21];
    float* out = (float*)d_out;

    // workspace layout, ~2.7 MB
    float* ws     = (float*)d_ws;
    float* xA     = ws;                     // (N, XS)
    float* xB     = xA + Nn * XS;           // (N, XS)
    float* xC     = xB + Nn * XS;           // (N, XS)
    float* Ei     = xC + Nn * XS;           // (N, 96)
    float* EjT    = Ei + NH;                // (96, N)
    float* Wt_hh  = EjT + NH;               // 96*288
    float* Wf     = Wt_hh + 27648;          // 96*288
    float* Wt_a1i = Wf + 27648;             // 96*96
    float* Wt_a1j = Wt_a1i + 9216;
    float* Wt_o1  = Wt_a1j + 9216;
    float* Wt_o2  = Wt_o1 + 9216;
    int*   bar    = (int*)(Wt_o2 + 9216);   // 4 grid-barrier counters

    // bar must be zeroed every replay (workspace is poisoned by harness)
    hipMemsetAsync(bar, 0, 4 * sizeof(int), stream);

    Params p;
    p.x_in = x_in; p.ei = ei; p.adj = adj;
    p.W_init = W_init; p.b_init = b_init;
    p.W_ggc = W_ggc; p.W_ih = W_ih; p.W_hh = W_hh;
    p.b_ih = b_ih; p.b_hh = b_hh;
    p.Wa1 = Wa1; p.ba1 = ba1; p.Wa2 = Wa2; p.ba2 = ba2;
    p.Wo1 = Wo1; p.bo1 = bo1; p.Wo2 = Wo2; p.bo2 = bo2;
    p.Wp1 = Wp1; p.bp1 = bp1; p.Wp2 = Wp2; p.bp2 = bp2;
    p.out = out;
    p.xA = xA; p.xB = xB; p.xC = xC; p.Ei = Ei; p.EjT = EjT;
    p.Wt_hh = Wt_hh; p.Wf = Wf; p.Wt_a1i = Wt_a1i; p.Wt_a1j = Wt_a1j;
    p.Wt_o1 = Wt_o1; p.Wt_o2 = Wt_o2;
    p.bar = bar;

    fused_kernel<<<NBLK, 1024, 0, stream>>>(p);
}

// Round 7
// 192.984 us; speedup vs baseline: 1.3032x; 1.3032x over previous
//
#include <hip/hip_runtime.h>

// Problem constants (from reference)
#define Nn 1024
#define Hh 96
#define Ee 16384
#define IN_K 9       // IN_RAW-1
#define IN_STRIDE 10 // x is (N, 10), we use first 9 cols
#define NH (Nn * Hh)
#define XS 128       // padded row stride for x-like (N,96) buffers
#define SLOTS 64     // CSR bucket capacity (Poisson(16) degree; P(>64) ~ 0)

__device__ __forceinline__ float sigf(float v) {
    return __builtin_amdgcn_rcpf(1.0f + __expf(-v));
}
__device__ __forceinline__ float tanhfast(float v) {
    float e = __expf(2.0f * v);
    return (e - 1.0f) * __builtin_amdgcn_rcpf(e + 1.0f);
}
__device__ __forceinline__ float leakyf(float v) {
    return v >= 0.0f ? v : 0.01f * v;
}

// ---------------- setup: transposes + Wf fold + init linear + zero deg -----
__global__ __launch_bounds__(256) void setup_kernel(
    const float* __restrict__ W_hh, const float* __restrict__ Wa1,
    const float* __restrict__ Wo1, const float* __restrict__ Wo2,
    const float* __restrict__ W_ggc, const float* __restrict__ W_ih,
    const float* __restrict__ x_in, const float* __restrict__ W_init,
    const float* __restrict__ b_init,
    float* __restrict__ Wt_hh, float* __restrict__ Wt_a1i,
    float* __restrict__ Wt_a1j, float* __restrict__ Wt_o1,
    float* __restrict__ Wt_o2, float* __restrict__ Wf,
    int* __restrict__ deg, float* __restrict__ xA)
{
    int gt = blockIdx.x * 256 + threadIdx.x;
    if (gt < Nn) deg[gt] = 0;
    if (gt < 64512) {   // transposes: Wt_hh 27648 + 4x9216
        int idx = gt;
        if (idx < 27648) {
            int k = idx / 288, c = idx % 288;
            Wt_hh[idx] = W_hh[c * 96 + k];
        } else if ((idx -= 27648) < 9216) {
            int k = idx / 96, h = idx % 96;
            Wt_a1i[idx] = Wa1[h * 192 + k];
        } else if ((idx -= 9216) < 9216) {
            int k = idx / 96, h = idx % 96;
            Wt_a1j[idx] = Wa1[h * 192 + 96 + k];
        } else if ((idx -= 9216) < 9216) {
            int k = idx / 96, j = idx % 96;
            Wt_o1[idx] = Wo1[j * 96 + k];
        } else {
            idx -= 9216;
            int k = idx / 96, j = idx % 96;
            Wt_o2[idx] = Wo2[j * 96 + k];
        }
    }
    if (gt < 27648) {   // Wf[k][c] = sum_j W_ggc[k][j] * W_ih[c][j]
        int k = gt / 288, c = gt % 288;
        const float* g = W_ggc + k * 96;
        const float* w = W_ih + c * 96;
        float acc = 0.0f;
        for (int j = 0; j < 96; ++j) acc += g[j] * w[j];
        Wf[gt] = acc;
    }
    if (gt < NH) {      // init linear
        int n = gt / Hh, j = gt - n * Hh;
        const float* xr = x_in + n * IN_STRIDE;
        const float* wr = W_init + j * IN_K;
        float acc = b_init[j];
#pragma unroll
        for (int k = 0; k < IN_K; ++k) acc += xr[k] * wr[k];
        xA[n * XS + j] = leakyf(acc);
    }
}

// ---------------- edges: CSR bucket scatter (needs zeroed deg) -------------
__global__ __launch_bounds__(256) void edges_kernel(
    const int* __restrict__ ei, int* __restrict__ deg, int* __restrict__ bucket)
{
    int e = blockIdx.x * 256 + threadIdx.x;
    if (e >= Ee) return;
    int src = ei[e];
    int tgt = ei[Ee + e];
    int slot = atomicAdd(&deg[tgt], 1);
    if (slot < SLOTS) bucket[tgt * SLOTS + slot] = src;
}

// ---------------- phase A: gather + GRU + attn projections -----------------
// 1 row/block, 384 threads = 4 k-quarters (q) x 96 h. Grid = 1024 ->
// 4 blocks/CU (24 waves/CU) for latency hiding. LDS ~15 KB.
__global__ __launch_bounds__(384, 4) void gru_kernel(
    const float* __restrict__ xA, const int* __restrict__ deg,
    const int* __restrict__ bucket,
    const float* __restrict__ Wf, const float* __restrict__ Wt_hh,
    const float* __restrict__ b_ih, const float* __restrict__ b_hh,
    const float* __restrict__ Wt_a1i, const float* __restrict__ Wt_a1j,
    const float* __restrict__ ba1,
    float* __restrict__ xB, float* __restrict__ Ei, float* __restrict__ EjT)
{
    __shared__ float Pq[4][Hh];        // gather partials per quarter
    __shared__ float Pm[Hh];           // combined mean
    __shared__ float Xr[Hh];           // x row
    __shared__ float Xo[Hh];           // GRU output row
    __shared__ float red6[4][Hh][6];   // gate dot partials [q][h][gate]
    __shared__ float redp[4][Hh][2];   // projection partials
    int tid = threadIdx.x;
    int q = tid / Hh;                  // 0..3
    int h = tid - q * Hh;
    int n = blockIdx.x;
    // gather partial: quarter q sums slots q, q+4, ... (bk[s] is wave-uniform)
    {
        int d = deg[n];
        int dc = d < SLOTS ? d : SLOTS;
        const int* bk = bucket + n * SLOTS;
        float acc = 0.0f;
        for (int s = q; s < dc; s += 4)
            acc += xA[bk[s] * XS + h];
        Pq[q][h] = acc;
        if (q == 0) Xr[h] = xA[n * XS + h];
    }
    __syncthreads();
    if (q == 0) {
        float inv = __builtin_amdgcn_rcpf(fmaxf((float)deg[n], 1.0f));
        Pm[h] = (Pq[0][h] + Pq[1][h] + Pq[2][h] + Pq[3][h]) * inv;
    }
    __syncthreads();
    // GRU partial dots over this thread's k-quarter (24 k)
    {
        const float* pf = Wf + h;
        const float* ph = Wt_hh + h;
        float gir = 0.f, giz = 0.f, gin = 0.f;
        float ghr = 0.f, ghz = 0.f, ghn = 0.f;
        int k0 = q * 24;
#pragma unroll 4
        for (int k = k0; k < k0 + 24; ++k) {
            float a = Pm[k];      // LDS broadcast
            float xv = Xr[k];     // LDS broadcast
            int o = k * 288;
            gir += a * pf[o];
            giz += a * pf[o + 96];
            gin += a * pf[o + 192];
            ghr += xv * ph[o];
            ghz += xv * ph[o + 96];
            ghn += xv * ph[o + 192];
        }
        red6[q][h][0] = gir;
        red6[q][h][1] = giz;
        red6[q][h][2] = gin;
        red6[q][h][3] = ghr;
        red6[q][h][4] = ghz;
        red6[q][h][5] = ghn;
    }
    __syncthreads();
    if (q == 0) {
        float gir = b_ih[h], giz = b_ih[Hh + h], gin = b_ih[2 * Hh + h];
        float ghr = b_hh[h], ghz = b_hh[Hh + h], ghn = b_hh[2 * Hh + h];
#pragma unroll
        for (int qq = 0; qq < 4; ++qq) {
            gir += red6[qq][h][0];
            giz += red6[qq][h][1];
            gin += red6[qq][h][2];
            ghr += red6[qq][h][3];
            ghz += red6[qq][h][4];
            ghn += red6[qq][h][5];
        }
        float rr = sigf(gir + ghr);
        float z = sigf(giz + ghz);
        float nn2 = tanhfast(gin + rr * ghn);
        float xo = (1.0f - z) * nn2 + z * Xr[h];
        xB[n * XS + h] = xo;
        Xo[h] = xo;
    }
    __syncthreads();
    // attention projection partials (24 k per thread)
    {
        const float* wi = Wt_a1i + h;
        const float* wj = Wt_a1j + h;
        float a = 0.0f, bb = 0.0f;
        int k0 = q * 24;
#pragma unroll 4
        for (int k = k0; k < k0 + 24; ++k) {
            float xv = Xo[k];     // LDS broadcast
            a += xv * wi[k * 96];
            bb += xv * wj[k * 96];
        }
        redp[q][h][0] = a;
        redp[q][h][1] = bb;
    }
    __syncthreads();
    if (q == 0) {
        float a = redp[0][h][0] + redp[1][h][0] + redp[2][h][0] + redp[3][h][0];
        float bb = redp[0][h][1] + redp[1][h][1] + redp[2][h][1] + redp[3][h][1];
        Ei[n * Hh + h] = __expf(-(a + ba1[h]));
        EjT[h * Nn + n] = __expf(-bb);
    }
}

// ---------------- phase B: coeffs + row-GEMM, 4 rows x FULL j per block ----
// Grid = 256, 1024 threads. Thread owns ONE j; one EjT vector load per k
// feeds all 4 rows. Ei/Wa2 read with wave-uniform indices -> s_load path.
// sm layout (floats): C @0 (4x1024), red @4096 (8x4x96=3072) = 28.7 KB.
__global__ __launch_bounds__(1024) void attn_kernel_u0(
    const float* __restrict__ Ei, const float* __restrict__ EjT,
    const float* __restrict__ Wa2, const float* __restrict__ ba2,
    const int* __restrict__ adj, const float* __restrict__ xB,
    float* __restrict__ xOut)
{
    __shared__ float sm[7168];
    int tid = threadIdx.x;
    int i0 = blockIdx.x * 4;
    {
        int j = tid;
        int m0 = adj[(i0 + 0) * Nn + j];
        int m1 = adj[(i0 + 1) * Nn + j];
        int m2 = adj[(i0 + 2) * Nn + j];
        int m3 = adj[(i0 + 3) * Nn + j];
        const float* e0 = Ei + i0 * Hh;       // uniform base
        float s0 = 0.f, s1 = 0.f, s2 = 0.f, s3 = 0.f;
#pragma unroll 8
        for (int k = 0; k < Hh; ++k) {
            float e = EjT[k * Nn + j];
            float wk = Wa2[k];                 // s_load
            s0 += __builtin_amdgcn_rcpf(fmaf(e0[k], e, 1.0f)) * wk;
            s1 += __builtin_amdgcn_rcpf(fmaf(e0[96 + k], e, 1.0f)) * wk;
            s2 += __builtin_amdgcn_rcpf(fmaf(e0[192 + k], e, 1.0f)) * wk;
            s3 += __builtin_amdgcn_rcpf(fmaf(e0[288 + k], e, 1.0f)) * wk;
        }
        float b2 = ba2[0];
        sm[0 * Nn + j] = (m0 == 1) ? sigf(s0 + b2) : 0.0f;
        sm[1 * Nn + j] = (m1 == 1) ? sigf(s1 + b2) : 0.0f;
        sm[2 * Nn + j] = (m2 == 1) ? sigf(s2 + b2) : 0.0f;
        sm[3 * Nn + j] = (m3 == 1) ? sigf(s3 + b2) : 0.0f;
    }
    __syncthreads();
    {
        int q = tid >> 7;
        int h = tid & 127;
        if (h < Hh) {
            int jb = q * 128;
            const float* xc = xB + jb * XS + h;
            const float* c0 = sm + 0 * Nn + jb;
            const float* c1 = sm + 1 * Nn + jb;
            const float* c2 = sm + 2 * Nn + jb;
            const float* c3 = sm + 3 * Nn + jb;
            float a0 = 0.f, a1 = 0.f, a2 = 0.f, a3 = 0.f;
#pragma unroll 4
            for (int j = 0; j < 128; ++j) {
                float xv = xc[j * XS];
                a0 += c0[j] * xv;
                a1 += c1[j] * xv;
                a2 += c2[j] * xv;
                a3 += c3[j] * xv;
            }
            sm[4096 + ((q * 4 + 0) * Hh) + h] = a0;
            sm[4096 + ((q * 4 + 1) * Hh) + h] = a1;
            sm[4096 + ((q * 4 + 2) * Hh) + h] = a2;
            sm[4096 + ((q * 4 + 3) * Hh) + h] = a3;
        }
    }
    __syncthreads();
    if (tid < 4 * Hh) {
        int r = tid / Hh, h = tid - r * Hh;
        float v = 0.f;
#pragma unroll
        for (int q = 0; q < 8; ++q)
            v += sm[4096 + ((q * 4 + r) * Hh) + h];
        xOut[(i0 + r) * XS + h] = v;
    }
}

__global__ __launch_bounds__(1024) void attn_kernel_u1(
    const float* __restrict__ Ei, const float* __restrict__ EjT,
    const float* __restrict__ Wa2, const float* __restrict__ ba2,
    const int* __restrict__ adj, const float* __restrict__ xB,
    const float* __restrict__ Wt_o1, const float* __restrict__ bo1,
    const float* __restrict__ Wt_o2, const float* __restrict__ bo2,
    const float* __restrict__ Wp1, const float* __restrict__ bp1,
    const float* __restrict__ Wp2, const float* __restrict__ bp2,
    float* __restrict__ out)
{
    __shared__ float sm[7168];
    __shared__ float hd[3][4][Hh];    // xout, t1, t2 for the fused head
    int tid = threadIdx.x;
    int i0 = blockIdx.x * 4;
    {
        int j = tid;
        int m0 = adj[(i0 + 0) * Nn + j];
        int m1 = adj[(i0 + 1) * Nn + j];
        int m2 = adj[(i0 + 2) * Nn + j];
        int m3 = adj[(i0 + 3) * Nn + j];
        const float* e0 = Ei + i0 * Hh;
        float s0 = 0.f, s1 = 0.f, s2 = 0.f, s3 = 0.f;
#pragma unroll 8
        for (int k = 0; k < Hh; ++k) {
            float e = EjT[k * Nn + j];
            float wk = Wa2[k];
            s0 += __builtin_amdgcn_rcpf(fmaf(e0[k], e, 1.0f)) * wk;
            s1 += __builtin_amdgcn_rcpf(fmaf(e0[96 + k], e, 1.0f)) * wk;
            s2 += __builtin_amdgcn_rcpf(fmaf(e0[192 + k], e, 1.0f)) * wk;
            s3 += __builtin_amdgcn_rcpf(fmaf(e0[288 + k], e, 1.0f)) * wk;
        }
        float b2 = ba2[0];
        sm[0 * Nn + j] = (m0 == 1) ? sigf(s0 + b2) : 0.0f;
        sm[1 * Nn + j] = (m1 == 1) ? sigf(s1 + b2) : 0.0f;
        sm[2 * Nn + j] = (m2 == 1) ? sigf(s2 + b2) : 0.0f;
        sm[3 * Nn + j] = (m3 == 1) ? sigf(s3 + b2) : 0.0f;
    }
    __syncthreads();
    {
        int q = tid >> 7;
        int h = tid & 127;
        if (h < Hh) {
            int jb = q * 128;
            const float* xc = xB + jb * XS + h;
            const float* c0 = sm + 0 * Nn + jb;
            const float* c1 = sm + 1 * Nn + jb;
            const float* c2 = sm + 2 * Nn + jb;
            const float* c3 = sm + 3 * Nn + jb;
            float a0 = 0.f, a1 = 0.f, a2 = 0.f, a3 = 0.f;
#pragma unroll 4
            for (int j = 0; j < 128; ++j) {
                float xv = xc[j * XS];
                a0 += c0[j] * xv;
                a1 += c1[j] * xv;
                a2 += c2[j] * xv;
                a3 += c3[j] * xv;
            }
            sm[4096 + ((q * 4 + 0) * Hh) + h] = a0;
            sm[4096 + ((q * 4 + 1) * Hh) + h] = a1;
            sm[4096 + ((q * 4 + 2) * Hh) + h] = a2;
            sm[4096 + ((q * 4 + 3) * Hh) + h] = a3;
        }
    }
    __syncthreads();
    if (tid < 4 * Hh) {
        int r = tid / Hh, h = tid - r * Hh;
        float v = 0.f;
#pragma unroll
        for (int q = 0; q < 8; ++q)
            v += sm[4096 + ((q * 4 + r) * Hh) + h];
        hd[0][r][h] = v;
    }
    __syncthreads();
    if (tid < 4 * Hh) {
        int r = tid / Hh, h = tid - r * Hh;
        const float* w = Wt_o1 + h;
        const float* xr = hd[0][r];
        float acc = bo1[h];
        for (int k = 0; k < Hh; ++k) acc += xr[k] * w[k * 96];
        hd[1][r][h] = leakyf(acc);
    }
    __syncthreads();
    if (tid < 4 * Hh) {
        int r = tid / Hh, h = tid - r * Hh;
        const float* w = Wt_o2 + h;
        const float* xr = hd[1][r];
        float acc = bo2[h];
        for (int k = 0; k < Hh; ++k) acc += xr[k] * w[k * 96];
        hd[2][r][h] = leakyf(acc);
    }
    __syncthreads();
    if (tid < 8) {
        int r = tid >> 1, which = tid & 1;
        const float* wp = which ? Wp2 : Wp1;
        const float* xr = hd[2][r];
        float acc = 0.f;
        for (int k = 0; k < Hh; ++k) acc += xr[k] * wp[k];
        float b = which ? bp2[0] : bp1[0];
        out[which * Nn + i0 + r] = sigf(acc + b);
    }
}

extern "C" void kernel_launch(void* const* d_in, const int* in_sizes, int n_in,
                              void* d_out, int out_size, void* d_ws, size_t ws_size,
                              hipStream_t stream)
{
    const float* x_in   = (const float*)d_in[0];
    const int*   ei     = (const int*)d_in[1];
    const int*   adj    = (const int*)d_in[2];
    const float* W_init = (const float*)d_in[3];
    const float* b_init = (const float*)d_in[4];
    const float* W_ggc  = (const float*)d_in[5];
    const float* W_ih   = (const float*)d_in[6];
    const float* W_hh   = (const float*)d_in[7];
    const float* b_ih   = (const float*)d_in[8];
    const float* b_hh   = (const float*)d_in[9];
    const float* Wa1    = (const float*)d_in[10];
    const float* ba1    = (const float*)d_in[11];
    const float* Wa2    = (const float*)d_in[12];
    const float* ba2    = (const float*)d_in[13];
    const float* Wo1    = (const float*)d_in[14];
    const float* bo1    = (const float*)d_in[15];
    const float* Wo2    = (const float*)d_in[16];
    const float* bo2    = (const float*)d_in[17];
    const float* Wp1    = (const float*)d_in[18];
    const float* bp1    = (const float*)d_in[19];
    const float* Wp2    = (const float*)d_in[20];
    const float* bp2    = (const float*)d_in[21];
    float* out = (float*)d_out;

    // workspace layout, ~2.5 MB
    float* ws     = (float*)d_ws;
    float* xA     = ws;                     // (N, XS)
    float* xB     = xA + Nn * XS;           // (N, XS)
    float* xC     = xB + Nn * XS;           // (N, XS)
    float* Ei     = xC + Nn * XS;           // (N, 96)
    float* EjT    = Ei + NH;                // (96, N)
    float* Wt_hh  = EjT + NH;               // 96*288
    float* Wf     = Wt_hh + 27648;          // 96*288
    float* Wt_a1i = Wf + 27648;             // 96*96
    float* Wt_a1j = Wt_a1i + 9216;
    float* Wt_o1  = Wt_a1j + 9216;
    float* Wt_o2  = Wt_o1 + 9216;
    int*   deg    = (int*)(Wt_o2 + 9216);   // (N)
    int*   bucket = deg + Nn;               // (N, SLOTS)

    setup_kernel<<<(NH + 255) / 256, 256, 0, stream>>>(
        W_hh, Wa1, Wo1, Wo2, W_ggc, W_ih, x_in, W_init, b_init,
        Wt_hh, Wt_a1i, Wt_a1j, Wt_o1, Wt_o2, Wf, deg, xA);
    edges_kernel<<<(Ee + 255) / 256, 256, 0, stream>>>(ei, deg, bucket);

    // unroll 0: xA -> xB -> xC
    gru_kernel<<<Nn, 384, 0, stream>>>(
        xA, deg, bucket, Wf, Wt_hh, b_ih, b_hh, Wt_a1i, Wt_a1j, ba1,
        xB, Ei, EjT);
    attn_kernel_u0<<<Nn / 4, 1024, 0, stream>>>(
        Ei, EjT, Wa2, ba2, adj, xB, xC);
    // unroll 1: xC -> xB -> (head fused) -> out
    gru_kernel<<<Nn, 384, 0, stream>>>(
        xC, deg, bucket, Wf, Wt_hh, b_ih, b_hh, Wt_a1i, Wt_a1j, ba1,
        xB, Ei, EjT);
    attn_kernel_u1<<<Nn / 4, 1024, 0, stream>>>(
        Ei, EjT, Wa2, ba2, adj, xB,
        Wt_o1, bo1, Wt_o2, bo2, Wp1, bp1, Wp2, bp2, out);
}